// Round 8
// baseline (344.728 us; speedup 1.0000x reference)
//
#include <hip/hip_runtime.h>

typedef unsigned short ushort;
typedef __bf16 bf16x8 __attribute__((ext_vector_type(8)));
typedef float f32x4 __attribute__((ext_vector_type(4)));

#define F_IN 256
#define CCH  128
#define BSH  7
#define BNODES 128
#define NBUCK 1024
#define CHUNK 2048

// ---------------- helpers ----------------
__device__ __forceinline__ ushort f2bf(float f) {
    union { float f; unsigned i; } u; u.f = f;
    unsigned r = u.i + 0x7fffu + ((u.i >> 16) & 1u);   // RNE
    return (ushort)(r >> 16);
}
__device__ __forceinline__ float2 bf2f2(unsigned u) {
    union { unsigned i; float f; } lo, hi;
    lo.i = u << 16;
    hi.i = u & 0xffff0000u;
    return make_float2(lo.f, hi.f);
}
__device__ __forceinline__ void gload_lds16(const void* g, void* l) {
    __builtin_amdgcn_global_load_lds((const __attribute__((address_space(1))) unsigned*)g,
                                     (__attribute__((address_space(3))) unsigned*)l, 16, 0, 0);
}

// ---------------- K1: per-chunk histogram (tiled histT) + weight cvt ----------------
// histT TILED: [(b>>4)][chunk][b&15] -> each 64B line = 16 buckets of ONE chunk (R7-proven).
// w1b PRE-SWIZZLED: within each 32-col k-tile, chunk c -> c ^ ((row>>1)&3).
__global__ __launch_bounds__(256)
void hist_cvt(const int* __restrict__ dst, int* __restrict__ histC, int* __restrict__ histT,
              int E, int nchunks, int ncp,
              const float* __restrict__ W1, const float* __restrict__ W2,
              ushort* __restrict__ w1b, ushort* __restrict__ w2b)
{
    const int blk = blockIdx.x, t = threadIdx.x;
    if (blk >= nchunks) {
        int i = (blk - nchunks) * 256 + t;
        if (i < CCH * F_IN) {
            int c  = i & 31;
            int cs = c ^ (((i >> 9) & 3) << 3);        // (row>>1)&3, row = i>>8
            w1b[(i & ~31) | cs] = f2bf(W1[i]);
        } else {
            int j = i - CCH * F_IN;
            if (j < CCH * CCH) w2b[j] = f2bf(W2[j]);
        }
        return;
    }
    __shared__ int h[NBUCK];
    for (int i = t; i < NBUCK; i += 256) h[i] = 0;
    __syncthreads();
    int cb = blk * CHUNK, ce = min(cb + CHUNK, E);
    for (int e = cb + t; e < ce; e += 256)
        atomicAdd(&h[dst[e] >> BSH], 1);
    __syncthreads();
    const int ncp16 = ncp * 16;
    for (int i = t; i < NBUCK; i += 256) {
        int v = h[i];
        histC[blk * NBUCK + i] = v;                            // chunk-major (partition scan 1)
        histT[(i >> 4) * ncp16 + blk * 16 + (i & 15)] = v;     // tiled (scan / partition scan 2)
    }
}

// ---------------- K2: per-bucket cross-chunk prefix, IN PLACE in tiled histT ----------------
// 64 blocks x 1024 threads: block B owns buckets 16B..16B+15 (one wave each) -> every 64B
// line of histT is read+written by ONE block (single XCD; no line ping-pong).
__global__ __launch_bounds__(1024)
void scan_buckets(int* __restrict__ histT, int* __restrict__ btot, int nchunks, int ncp)
{
    const int w = threadIdx.x >> 6;                 // 0..15 = bucket within tile
    const int b = blockIdx.x * 16 + w;
    const int lane = threadIdx.x & 63;
    const int tb = blockIdx.x * (ncp * 16) + w;
    int carry = 0;
    for (int c = 0; c < nchunks; c += 64) {
        int idx = c + lane;
        int v = (idx < nchunks) ? histT[tb + idx * 16] : 0;
        int inc = v;
#pragma unroll
        for (int off = 1; off < 64; off <<= 1) {
            int x = __shfl_up(inc, off, 64);
            if (lane >= off) inc += x;
        }
        if (idx < nchunks) histT[tb + idx * 16] = carry + inc - v;   // exclusive prefix in place
        carry += __shfl(inc, 63, 64);
    }
    if (lane == 0) btot[b] = carry;
}

// ---------------- device body: partition (shuffle scans, direct write) ----------------
// LDS carve (u32): lcur(1024) off(1024) wsum(16) = 8.2 KB.  4 barriers (was ~36).
// Single edge pass: pairs[off[b] + p] written straight from the atomic slot; write locality
// comes from the XCD-contiguous chunk remap (R7) -> a line's ~8 writer chunks share one L2.
__device__ __forceinline__ void partition_body(unsigned* smem4,
    const int* __restrict__ src, const int* __restrict__ dst,
    const int* __restrict__ histC, const int* __restrict__ histPre,
    const int* __restrict__ btot, int* __restrict__ gbase,
    unsigned* __restrict__ pairs, int E, int ncp, int blk)
{
    int* lcur = (int*)smem4;               // NBUCK
    int* off  = lcur + NBUCK;              // NBUCK: global_base - lbase
    int* wsum = off + NBUCK;               // 4
    const int t = threadIdx.x;
    const int wv = t >> 6, lane = t & 63;

    // ---- scan 1: this chunk's hist -> lbase (regs) / lcur ----
    int4 cv = *(const int4*)&histC[blk * NBUCK + 4 * t];
    int tsum = cv.x + cv.y + cv.z + cv.w;
    int inc = tsum;
#pragma unroll
    for (int o = 1; o < 64; o <<= 1) {
        int x = __shfl_up(inc, o, 64);
        if (lane >= o) inc += x;
    }
    if (lane == 63) wsum[wv] = inc;
    __syncthreads();
    int woff = 0;
    if (wv > 0) woff += wsum[0];
    if (wv > 1) woff += wsum[1];
    if (wv > 2) woff += wsum[2];
    int l0 = woff + inc - tsum, l1 = l0 + cv.x, l2 = l1 + cv.y, l3 = l2 + cv.z;
    lcur[4 * t] = l0; lcur[4 * t + 1] = l1; lcur[4 * t + 2] = l2; lcur[4 * t + 3] = l3;

    // ---- scan 2: bucket totals -> global bases; off = base + pref - lbase ----
    int4 bt = *(const int4*)&btot[4 * t];
    int bsum = bt.x + bt.y + bt.z + bt.w;
    int binc = bsum;
#pragma unroll
    for (int o = 1; o < 64; o <<= 1) {
        int x = __shfl_up(binc, o, 64);
        if (lane >= o) binc += x;
    }
    __syncthreads();                        // wsum reuse safe
    if (lane == 63) wsum[wv] = binc;
    __syncthreads();
    int bwoff = 0;
    if (wv > 0) bwoff += wsum[0];
    if (wv > 1) bwoff += wsum[1];
    if (wv > 2) bwoff += wsum[2];
    int b0 = bwoff + binc - bsum, b1 = b0 + bt.x, b2 = b1 + bt.y, b3 = b2 + bt.z;
    if (blk == 0) {
        *(int4*)&gbase[4 * t] = make_int4(b0, b1, b2, b3);
        if (t == 255) gbase[NBUCK] = b3 + bt.w;
    }
    // tiled per-chunk prefix (in-place scanned histT): rows 4t..4t+3, col blk -> one int4
    int4 pf = *(const int4*)&histPre[(t >> 2) * (ncp * 16) + blk * 16 + (t & 3) * 4];
    off[4 * t]     = b0 + pf.x - l0;
    off[4 * t + 1] = b1 + pf.y - l1;
    off[4 * t + 2] = b2 + pf.z - l2;
    off[4 * t + 3] = b3 + pf.w - l3;
    __syncthreads();

    // ---- single edge pass: direct write ----
    const int cb = blk * CHUNK, ce = min(cb + CHUNK, E);
    for (int e = cb + t; e < ce; e += 256) {
        int d = dst[e];
        int b = d >> BSH;
        unsigned packed = ((unsigned)src[e] << BSH) | (unsigned)(d & (BNODES - 1));
        int p = atomicAdd(&lcur[b], 1);
        pairs[off[b] + p] = packed;
    }
}

// ---------------- device body: per-bucket CSR finalize (shuffle scan) ----------------
__device__ __forceinline__ void csr_body(unsigned* smem4,
    const unsigned* __restrict__ pairs, const int* __restrict__ base,
    int* __restrict__ row_start, float* __restrict__ dinv,
    unsigned* __restrict__ csr, int N, int E, int b, int lastb)
{
    int* deg  = (int*)smem4;               // 128
    int* cur  = deg + BNODES;              // 128
    int* wsum = cur + BNODES;              // 2
    const int t = threadIdx.x;
    if (t < BNODES) deg[t] = 0;
    __syncthreads();
    const int rb = base[b], re = base[b + 1];
    for (int e = rb + t; e < re; e += 256)
        atomicAdd(&deg[pairs[e] & (BNODES - 1)], 1);
    __syncthreads();
    int v = (t < BNODES) ? deg[t] : 0;
    int inc = v;
#pragma unroll
    for (int o = 1; o < 64; o <<= 1) {
        int x = __shfl_up(inc, o, 64);
        if ((t & 63) >= o) inc += x;
    }
    if (t < BNODES && (t & 63) == 63) wsum[t >> 6] = inc;
    __syncthreads();
    const int n0 = b << BSH;
    if (t < BNODES) {
        int excl = inc - v + ((t >= 64) ? wsum[0] : 0);
        cur[t] = rb + excl;
        if (n0 + t < N) {
            row_start[n0 + t] = rb + excl;
            dinv[n0 + t] = rsqrtf((float)v + 1.0f);
        }
    }
    if (b == lastb && t == 0) row_start[N] = E;
    __syncthreads();
    for (int e = rb + t; e < re; e += 256) {
        unsigned p = pairs[e];
        int slot = atomicAdd(&cur[p & (BNODES - 1)], 1);
        csr[slot] = p >> BSH;
    }
}

// ---------------- device body: fused GEMM  zq = relu(x@W1^T+b1) @ W2^T ----------------
// [R3 PMC: bank conflicts 3.08M->200K (swizzles verified). VGPR uncapped (R2 spill lesson).
//  dinv applied in gather. Row clamp (R6-proven).]
__device__ __forceinline__ void gemm_body(unsigned* smem4,
    const float* __restrict__ X, const ushort* __restrict__ W1b,
    const ushort* __restrict__ W2b, const float* __restrict__ b1,
    ushort* __restrict__ Zq, int M, int m0)
{
    ushort* smem = (ushort*)smem4;          // 32768 B: dbuf k-tiles, aliased by Ht[128][128]
    ushort* Ht = smem;
    const int tid  = threadIdx.x;
    const int wave = tid >> 6, lane = tid & 63;
    const int wm = (wave & 1) * 64, wn = (wave >> 1) * 64;
    const int lr = lane & 15, lq = lane >> 4;

    const int arow = tid >> 2;
    const int aq   = tid & 3;

    float4 ar[2][2];
    auto loadX = [&](int k0) {
#pragma unroll
        for (int it = 0; it < 2; it++) {
            int grow = min(m0 + arow + it * 64, M - 1);        // clamp, no branch
            const float* p = &X[(long)grow * F_IN + k0 + aq * 8];
            ar[it][0] = *(const float4*)p;
            ar[it][1] = *(const float4*)(p + 4);
        }
    };
    auto writeA = [&](ushort* As) {
#pragma unroll
        for (int it = 0; it < 2; it++) {
            int row = arow + it * 64;
            ushort u[8] = { f2bf(ar[it][0].x), f2bf(ar[it][0].y), f2bf(ar[it][0].z), f2bf(ar[it][0].w),
                            f2bf(ar[it][1].x), f2bf(ar[it][1].y), f2bf(ar[it][1].z), f2bf(ar[it][1].w) };
            *(uint4*)&As[row * 32 + ((aq ^ ((row >> 1) & 3)) << 3)] = *(uint4*)u;
        }
    };
    auto stageB = [&](int k0, ushort* Bs) {
#pragma unroll
        for (int it = 0; it < 2; it++) {
            int r0 = wave * 32 + it * 16;                        // wave-uniform LDS dest
            const ushort* g = &W1b[(long)(r0 + (lane >> 2)) * F_IN + k0 + (lane & 3) * 8];
            gload_lds16(g, &Bs[r0 * 32]);
        }
    };

    // ---- phase A: acc = x @ W1^T (K=256) ----
    f32x4 acc[4][4] = {};
    loadX(0);
    stageB(0, smem + 4096);
    writeA(smem);
    __syncthreads();
    for (int k0 = 0; k0 < F_IN; k0 += 32) {
        const int cur = (k0 >> 5) & 1;
        ushort* As = smem + cur * 8192;
        ushort* Bs = As + 4096;
        const bool more = (k0 + 32 < F_IN);
        if (more) {
            stageB(k0 + 32, smem + (cur ^ 1) * 8192 + 4096);
            loadX(k0 + 32);
        }
        bf16x8 af[4], bfr[4];
#pragma unroll
        for (int t4 = 0; t4 < 4; t4++) {
            int ra = wm + t4 * 16 + lr;
            int rb = wn + t4 * 16 + lr;
            af[t4]  = *(bf16x8*)&As[ra * 32 + ((lq ^ ((ra >> 1) & 3)) << 3)];
            bfr[t4] = *(bf16x8*)&Bs[rb * 32 + ((lq ^ ((rb >> 1) & 3)) << 3)];
        }
#pragma unroll
        for (int i = 0; i < 4; i++)
#pragma unroll
            for (int j = 0; j < 4; j++)
                acc[i][j] = __builtin_amdgcn_mfma_f32_16x16x32_bf16(af[i], bfr[j], acc[i][j], 0, 0, 0);
        if (more) writeA(smem + (cur ^ 1) * 8192);
        __syncthreads();
    }

    // prefetch W2 frags for k0=0
    uint4 wb[2][4];
#pragma unroll
    for (int t4 = 0; t4 < 4; t4++)
        wb[0][t4] = *(const uint4*)&W2b[(long)(wn + t4 * 16 + lr) * CCH + lq * 8];

    // ---- epilogue A: h = relu(acc + b1) -> Ht (swizzled) ----
    {
        float bv[4];
#pragma unroll
        for (int j = 0; j < 4; j++) bv[j] = b1[wn + j * 16 + lr];
#pragma unroll
        for (int i = 0; i < 4; i++)
#pragma unroll
            for (int r = 0; r < 4; r++) {
                int row = wm + i * 16 + lq * 4 + r;
                int rx  = (row & 7) << 3;
#pragma unroll
                for (int j = 0; j < 4; j++)
                    Ht[row * 128 + ((wn + j * 16 + lr) ^ rx)] = f2bf(fmaxf(acc[i][j][r] + bv[j], 0.f));
            }
    }
    __syncthreads();

    // ---- phase B: acc2 = h @ W2^T (K=128), barrier-free ----
    f32x4 acc2[4][4] = {};
#pragma unroll
    for (int kk = 0; kk < 4; kk++) {
        const int k0 = kk * 32;
        if (kk < 3) {
#pragma unroll
            for (int t4 = 0; t4 < 4; t4++)
                wb[(kk + 1) & 1][t4] =
                    *(const uint4*)&W2b[(long)(wn + t4 * 16 + lr) * CCH + k0 + 32 + lq * 8];
        }
        bf16x8 af[4];
#pragma unroll
        for (int t4 = 0; t4 < 4; t4++) {
            int ra = wm + t4 * 16 + lr;
            af[t4] = *(bf16x8*)&Ht[ra * 128 + ((k0 + lq * 8) ^ ((ra & 7) << 3))];
        }
#pragma unroll
        for (int i = 0; i < 4; i++)
#pragma unroll
            for (int j = 0; j < 4; j++)
                acc2[i][j] = __builtin_amdgcn_mfma_f32_16x16x32_bf16(af[i], *(bf16x8*)&wb[kk & 1][j],
                                                                     acc2[i][j], 0, 0, 0);
    }
    __syncthreads();

    // ---- epilogue B: z -> Ht (swizzled) -> coalesced store ----
#pragma unroll
    for (int i = 0; i < 4; i++)
#pragma unroll
        for (int r = 0; r < 4; r++) {
            int row = wm + i * 16 + lq * 4 + r;
            int rx  = (row & 7) << 3;
#pragma unroll
            for (int j = 0; j < 4; j++)
                Ht[row * 128 + ((wn + j * 16 + lr) ^ rx)] = f2bf(acc2[i][j][r]);
        }
    __syncthreads();
    {
        int colq = tid & 15, row0 = tid >> 4;
#pragma unroll
        for (int i = 0; i < 8; i++) {
            int row = row0 + i * 16;
            if (m0 + row < M)
                *(uint4*)&Zq[(long)(m0 + row) * CCH + colq * 8] =
                    *(uint4*)&Ht[row * 128 + ((colq * 8) ^ ((row & 7) << 3))];
        }
    }
}

// ---------------- U1: partition (XCD-contiguous chunk remap, FIRST) ∪ gemm half A ----------------
__global__ __launch_bounds__(256)
void u_part_gemm(const int* __restrict__ src, const int* __restrict__ dst,
                 const int* __restrict__ histC, const int* __restrict__ histPre,
                 const int* __restrict__ btot, int* __restrict__ gbase,
                 unsigned* __restrict__ pairs, int E, int ncp, int nchunks,
                 const float* __restrict__ X, const ushort* __restrict__ W1b,
                 const ushort* __restrict__ W2b, const float* __restrict__ b1,
                 ushort* __restrict__ Zq, int M)
{
    __shared__ unsigned smem4[8192];    // 32 KB, carved per path
    const int bid = blockIdx.x;
    if (bid < nchunks) {
        const int x = bid & 7, i = bid >> 3;
        const int q = nchunks >> 3, r = nchunks & 7;
        const int chunk = (x < r) ? x * (q + 1) + i : r * (q + 1) + (x - r) * q + i;
        partition_body(smem4, src, dst, histC, histPre, btot, gbase, pairs, E, ncp, chunk);
    } else {
        gemm_body(smem4, X, W1b, W2b, b1, Zq, M, (bid - nchunks) * 128);
    }
}

// ---------------- U2: bucket CSR (FIRST) ∪ gemm half B ----------------
__global__ __launch_bounds__(256)
void u_csr_gemm(const unsigned* __restrict__ pairs, const int* __restrict__ base,
                int* __restrict__ row_start, float* __restrict__ dinv,
                unsigned* __restrict__ csr, int N, int E, int nbuck, int ngA,
                const float* __restrict__ X, const ushort* __restrict__ W1b,
                const ushort* __restrict__ W2b, const float* __restrict__ b1,
                ushort* __restrict__ Zq, int M)
{
    __shared__ unsigned smem4[8192];
    const int bid = blockIdx.x;
    if (bid < nbuck)
        csr_body(smem4, pairs, base, row_start, dinv, csr, N, E, bid, nbuck - 1);
    else
        gemm_body(smem4, X, W1b, W2b, b1, Zq, M, (ngA + bid - nbuck) * 128);
}

// ---------------- K6: gather (dinv[src]*dinv[dst] applied here), 16-deep MLP ----------------
__global__ __launch_bounds__(256)
void gather_nodes(const unsigned* __restrict__ zq, const unsigned* __restrict__ csr,
                  const int* __restrict__ row_start, const float* __restrict__ dinv,
                  const float* __restrict__ b2, float* __restrict__ out, int N)
{
    const int node = blockIdx.x * 4 + (threadIdx.x >> 6);
    const int lane = threadIdx.x & 63;
    if (node >= N) return;

    const float di = dinv[node];
    float2 zs = bf2f2(zq[(long)node * 64 + lane]);
    float acc0 = di * zs.x, acc1 = di * zs.y;      // self-loop: dinv[d]*z[d]

    const int rs = row_start[node];
    const int re = row_start[node + 1];
    int j = rs;
    for (; j + 16 <= re; j += 16) {
        unsigned sI[16], zv[16];
        float dv[16];
#pragma unroll
        for (int q = 0; q < 16; q++) sI[q] = csr[j + q];
#pragma unroll
        for (int q = 0; q < 16; q++) zv[q] = zq[(long)sI[q] * 64 + lane];
#pragma unroll
        for (int q = 0; q < 16; q++) dv[q] = dinv[sI[q]];
#pragma unroll
        for (int q = 0; q < 16; q++) { float2 f = bf2f2(zv[q]); acc0 += dv[q] * f.x; acc1 += dv[q] * f.y; }
    }
    for (; j + 4 <= re; j += 4) {
        unsigned sI[4], zv[4];
        float dv[4];
#pragma unroll
        for (int q = 0; q < 4; q++) sI[q] = csr[j + q];
#pragma unroll
        for (int q = 0; q < 4; q++) zv[q] = zq[(long)sI[q] * 64 + lane];
#pragma unroll
        for (int q = 0; q < 4; q++) dv[q] = dinv[sI[q]];
#pragma unroll
        for (int q = 0; q < 4; q++) { float2 f = bf2f2(zv[q]); acc0 += dv[q] * f.x; acc1 += dv[q] * f.y; }
    }
    for (; j < re; j++) {
        unsigned s = csr[j];
        float ds = dinv[s];
        float2 f = bf2f2(zq[(long)s * 64 + lane]);
        acc0 += ds * f.x; acc1 += ds * f.y;
    }

    float2 o;
    o.x = b2[lane * 2 + 0] + di * acc0;
    o.y = b2[lane * 2 + 1] + di * acc1;
    *(float2*)&out[(long)node * CCH + lane * 2] = o;
}

extern "C" void kernel_launch(void* const* d_in, const int* in_sizes, int n_in,
                              void* d_out, int out_size, void* d_ws, size_t ws_size,
                              hipStream_t stream)
{
    const float* x  = (const float*)d_in[0];
    const int*   ei = (const int*)d_in[1];
    const float* W1 = (const float*)d_in[2];
    const float* b1 = (const float*)d_in[3];
    const float* W2 = (const float*)d_in[4];
    const float* b2 = (const float*)d_in[5];
    float* out = (float*)d_out;

    const int N = in_sizes[0] / F_IN;
    const int E = in_sizes[1] / 2;
    const int* src = ei;
    const int* dst = ei + E;

    const int nchunks = (E + CHUNK - 1) / CHUNK;        // 782
    const int ncp     = (nchunks + 63) & ~63;           // 832
    const int nbuck   = (N + BNODES - 1) / BNODES;      // 782
    const int ngrid   = (N + 127) / 128;                // 782
    const int ngA     = (ngrid + 1) / 2;                // 391 (gemm half A)
    const int ngB     = ngrid - ngA;                    // 391 (gemm half B)
    const int ncvt    = (CCH * F_IN + CCH * CCH + 255) / 256;

    char* ws = (char*)d_ws;
    ushort* zq    = (ushort*)ws;   ws += (size_t)N * CCH * 2;
    ushort* w1b   = (ushort*)ws;   ws += (size_t)CCH * F_IN * 2;
    ushort* w2b   = (ushort*)ws;   ws += (size_t)CCH * CCH * 2;
    unsigned* prs = (unsigned*)ws; ws += (size_t)E * 4;
    unsigned* csr = (unsigned*)ws; ws += (size_t)E * 4;
    int* rstart   = (int*)ws;      ws += ((size_t)N + 1) * 4;
    float* dinv   = (float*)ws;    ws += (size_t)N * 4;
    int* histC    = (int*)ws;      ws += (size_t)nchunks * NBUCK * 4;
    int* histT    = (int*)ws;      ws += (size_t)NBUCK * ncp * 4;
    int* btot     = (int*)ws;      ws += NBUCK * 4;
    int* gbase    = (int*)ws;      ws += (NBUCK + 1) * 4;

    // K1: histogram (tiled histT) + weight cvt
    hist_cvt<<<nchunks + ncvt, 256, 0, stream>>>(dst, histC, histT, E, nchunks, ncp, W1, W2, w1b, w2b);
    // K2: bucket prefix IN PLACE in tiled histT (64 blocks x 16 buckets)
    scan_buckets<<<NBUCK / 16, 1024, 0, stream>>>(histT, btot, nchunks, ncp);
    // U1: partition (XCD-remapped, first) ∪ gemm-half-A
    u_part_gemm<<<nchunks + ngA, 256, 0, stream>>>(src, dst, histC, histT, btot, gbase, prs,
                                                   E, ncp, nchunks, x, w1b, w2b, b1, zq, N);
    // U2: bucket-CSR (first) ∪ gemm-half-B
    u_csr_gemm<<<nbuck + ngB, 256, 0, stream>>>(prs, gbase, rstart, dinv, csr, N, E,
                                                nbuck, ngA, x, w1b, w2b, b1, zq, N);
    // K6: aggregate (applies dinv[src] * dinv[dst])
    gather_nodes<<<(N + 3) / 4, 256, 0, stream>>>((const unsigned*)zq, csr, rstart, dinv, b2, out, N);
}

// Round 9
// 332.458 us; speedup vs baseline: 1.0369x; 1.0369x over previous
//
#include <hip/hip_runtime.h>

typedef unsigned short ushort;
typedef __bf16 bf16x8 __attribute__((ext_vector_type(8)));
typedef float f32x4 __attribute__((ext_vector_type(4)));

#define F_IN 256
#define CCH  128
#define BSH  7
#define BNODES 128
#define NBUCK 1024
#define CHUNK 2048

// ---------------- helpers ----------------
__device__ __forceinline__ ushort f2bf(float f) {
    union { float f; unsigned i; } u; u.f = f;
    unsigned r = u.i + 0x7fffu + ((u.i >> 16) & 1u);   // RNE
    return (ushort)(r >> 16);
}
__device__ __forceinline__ float2 bf2f2(unsigned u) {
    union { unsigned i; float f; } lo, hi;
    lo.i = u << 16;
    hi.i = u & 0xffff0000u;
    return make_float2(lo.f, hi.f);
}
__device__ __forceinline__ void gload_lds16(const void* g, void* l) {
    __builtin_amdgcn_global_load_lds((const __attribute__((address_space(1))) unsigned*)g,
                                     (__attribute__((address_space(3))) unsigned*)l, 16, 0, 0);
}

// ---------------- K0: weight cvt (w1b PRE-SWIZZLED). Tiny; must precede U0's gemm ----------------
__global__ __launch_bounds__(256)
void cvt_w(const float* __restrict__ W1, const float* __restrict__ W2,
           ushort* __restrict__ w1b, ushort* __restrict__ w2b)
{
    int i = blockIdx.x * 256 + threadIdx.x;
    if (i < CCH * F_IN) {
        int c  = i & 31;
        int cs = c ^ (((i >> 9) & 3) << 3);        // (row>>1)&3, row = i>>8
        w1b[(i & ~31) | cs] = f2bf(W1[i]);
    } else {
        int j = i - CCH * F_IN;
        if (j < CCH * CCH) w2b[j] = f2bf(W2[j]);
    }
}

// ---------------- device body: per-chunk histogram (tiled histT) ----------------
// histT TILED: [(b>>4)][chunk][b&15] -> each 64B line = 16 buckets of ONE chunk (R7-proven).
__device__ __forceinline__ void hist_body(unsigned* smem4,
    const int* __restrict__ dst, int* __restrict__ histC, int* __restrict__ histT,
    int E, int ncp, int blk)
{
    int* h = (int*)smem4;                  // NBUCK ints = 4 KB
    const int t = threadIdx.x;
    for (int i = t; i < NBUCK; i += 256) h[i] = 0;
    __syncthreads();
    int cb = blk * CHUNK, ce = min(cb + CHUNK, E);
    for (int e = cb + t; e < ce; e += 256)
        atomicAdd(&h[dst[e] >> BSH], 1);
    __syncthreads();
    const int ncp16 = ncp * 16;
    for (int i = t; i < NBUCK; i += 256) {
        int v = h[i];
        histC[blk * NBUCK + i] = v;                            // chunk-major (partition scan 1)
        histT[(i >> 4) * ncp16 + blk * 16 + (i & 15)] = v;     // tiled (scan / partition scan 2)
    }
}

// ---------------- K2: per-bucket cross-chunk prefix, IN PLACE in tiled histT ----------------
__global__ __launch_bounds__(1024)
void scan_buckets(int* __restrict__ histT, int* __restrict__ btot, int nchunks, int ncp)
{
    const int w = threadIdx.x >> 6;                 // 0..15 = bucket within tile
    const int b = blockIdx.x * 16 + w;
    const int lane = threadIdx.x & 63;
    const int tb = blockIdx.x * (ncp * 16) + w;
    int carry = 0;
    for (int c = 0; c < nchunks; c += 64) {
        int idx = c + lane;
        int v = (idx < nchunks) ? histT[tb + idx * 16] : 0;
        int inc = v;
#pragma unroll
        for (int off = 1; off < 64; off <<= 1) {
            int x = __shfl_up(inc, off, 64);
            if (lane >= off) inc += x;
        }
        if (idx < nchunks) histT[tb + idx * 16] = carry + inc - v;   // exclusive prefix in place
        carry += __shfl(inc, 63, 64);
    }
    if (lane == 0) btot[b] = carry;
}

// ---------------- device body: partition (shuffle scans, direct write; R8-verified) ----------------
__device__ __forceinline__ void partition_body(unsigned* smem4,
    const int* __restrict__ src, const int* __restrict__ dst,
    const int* __restrict__ histC, const int* __restrict__ histPre,
    const int* __restrict__ btot, int* __restrict__ gbase,
    unsigned* __restrict__ pairs, int E, int ncp, int blk)
{
    int* lcur = (int*)smem4;               // NBUCK
    int* off  = lcur + NBUCK;              // NBUCK: global_base - lbase
    int* wsum = off + NBUCK;               // 4
    const int t = threadIdx.x;
    const int wv = t >> 6, lane = t & 63;

    // ---- scan 1: this chunk's hist -> lbase (regs) / lcur ----
    int4 cv = *(const int4*)&histC[blk * NBUCK + 4 * t];
    int tsum = cv.x + cv.y + cv.z + cv.w;
    int inc = tsum;
#pragma unroll
    for (int o = 1; o < 64; o <<= 1) {
        int x = __shfl_up(inc, o, 64);
        if (lane >= o) inc += x;
    }
    if (lane == 63) wsum[wv] = inc;
    __syncthreads();
    int woff = 0;
    if (wv > 0) woff += wsum[0];
    if (wv > 1) woff += wsum[1];
    if (wv > 2) woff += wsum[2];
    int l0 = woff + inc - tsum, l1 = l0 + cv.x, l2 = l1 + cv.y, l3 = l2 + cv.z;
    lcur[4 * t] = l0; lcur[4 * t + 1] = l1; lcur[4 * t + 2] = l2; lcur[4 * t + 3] = l3;

    // ---- scan 2: bucket totals -> global bases; off = base + pref - lbase ----
    int4 bt = *(const int4*)&btot[4 * t];
    int bsum = bt.x + bt.y + bt.z + bt.w;
    int binc = bsum;
#pragma unroll
    for (int o = 1; o < 64; o <<= 1) {
        int x = __shfl_up(binc, o, 64);
        if (lane >= o) binc += x;
    }
    __syncthreads();                        // wsum reuse safe
    if (lane == 63) wsum[wv] = binc;
    __syncthreads();
    int bwoff = 0;
    if (wv > 0) bwoff += wsum[0];
    if (wv > 1) bwoff += wsum[1];
    if (wv > 2) bwoff += wsum[2];
    int b0 = bwoff + binc - bsum, b1 = b0 + bt.x, b2 = b1 + bt.y, b3 = b2 + bt.z;
    if (blk == 0) {
        *(int4*)&gbase[4 * t] = make_int4(b0, b1, b2, b3);
        if (t == 255) gbase[NBUCK] = b3 + bt.w;
    }
    // tiled per-chunk prefix (in-place scanned histT): rows 4t..4t+3, col blk -> one int4
    int4 pf = *(const int4*)&histPre[(t >> 2) * (ncp * 16) + blk * 16 + (t & 3) * 4];
    off[4 * t]     = b0 + pf.x - l0;
    off[4 * t + 1] = b1 + pf.y - l1;
    off[4 * t + 2] = b2 + pf.z - l2;
    off[4 * t + 3] = b3 + pf.w - l3;
    __syncthreads();

    // ---- single edge pass: direct write (locality via XCD-contiguous chunk remap) ----
    const int cb = blk * CHUNK, ce = min(cb + CHUNK, E);
    for (int e = cb + t; e < ce; e += 256) {
        int d = dst[e];
        int b = d >> BSH;
        unsigned packed = ((unsigned)src[e] << BSH) | (unsigned)(d & (BNODES - 1));
        int p = atomicAdd(&lcur[b], 1);
        pairs[off[b] + p] = packed;
    }
}

// ---------------- device body: per-bucket CSR finalize (shuffle scan; R8-verified) ----------------
__device__ __forceinline__ void csr_body(unsigned* smem4,
    const unsigned* __restrict__ pairs, const int* __restrict__ base,
    int* __restrict__ row_start, float* __restrict__ dinv,
    unsigned* __restrict__ csr, int N, int E, int b, int lastb)
{
    int* deg  = (int*)smem4;               // 128
    int* cur  = deg + BNODES;              // 128
    int* wsum = cur + BNODES;              // 2
    const int t = threadIdx.x;
    if (t < BNODES) deg[t] = 0;
    __syncthreads();
    const int rb = base[b], re = base[b + 1];
    for (int e = rb + t; e < re; e += 256)
        atomicAdd(&deg[pairs[e] & (BNODES - 1)], 1);
    __syncthreads();
    int v = (t < BNODES) ? deg[t] : 0;
    int inc = v;
#pragma unroll
    for (int o = 1; o < 64; o <<= 1) {
        int x = __shfl_up(inc, o, 64);
        if ((t & 63) >= o) inc += x;
    }
    if (t < BNODES && (t & 63) == 63) wsum[t >> 6] = inc;
    __syncthreads();
    const int n0 = b << BSH;
    if (t < BNODES) {
        int excl = inc - v + ((t >= 64) ? wsum[0] : 0);
        cur[t] = rb + excl;
        if (n0 + t < N) {
            row_start[n0 + t] = rb + excl;
            dinv[n0 + t] = rsqrtf((float)v + 1.0f);
        }
    }
    if (b == lastb && t == 0) row_start[N] = E;
    __syncthreads();
    for (int e = rb + t; e < re; e += 256) {
        unsigned p = pairs[e];
        int slot = atomicAdd(&cur[p & (BNODES - 1)], 1);
        csr[slot] = p >> BSH;
    }
}

// ---------------- device body: fused GEMM  zq = relu(x@W1^T+b1) @ W2^T ----------------
// [R3 PMC: bank conflicts 3.08M->200K (swizzles verified). VGPR uncapped (R2 spill lesson).
//  dinv applied in gather. Row clamp (R6-proven).]
__device__ __forceinline__ void gemm_body(unsigned* smem4,
    const float* __restrict__ X, const ushort* __restrict__ W1b,
    const ushort* __restrict__ W2b, const float* __restrict__ b1,
    ushort* __restrict__ Zq, int M, int m0)
{
    ushort* smem = (ushort*)smem4;          // 32768 B: dbuf k-tiles, aliased by Ht[128][128]
    ushort* Ht = smem;
    const int tid  = threadIdx.x;
    const int wave = tid >> 6, lane = tid & 63;
    const int wm = (wave & 1) * 64, wn = (wave >> 1) * 64;
    const int lr = lane & 15, lq = lane >> 4;

    const int arow = tid >> 2;
    const int aq   = tid & 3;

    float4 ar[2][2];
    auto loadX = [&](int k0) {
#pragma unroll
        for (int it = 0; it < 2; it++) {
            int grow = min(m0 + arow + it * 64, M - 1);        // clamp, no branch
            const float* p = &X[(long)grow * F_IN + k0 + aq * 8];
            ar[it][0] = *(const float4*)p;
            ar[it][1] = *(const float4*)(p + 4);
        }
    };
    auto writeA = [&](ushort* As) {
#pragma unroll
        for (int it = 0; it < 2; it++) {
            int row = arow + it * 64;
            ushort u[8] = { f2bf(ar[it][0].x), f2bf(ar[it][0].y), f2bf(ar[it][0].z), f2bf(ar[it][0].w),
                            f2bf(ar[it][1].x), f2bf(ar[it][1].y), f2bf(ar[it][1].z), f2bf(ar[it][1].w) };
            *(uint4*)&As[row * 32 + ((aq ^ ((row >> 1) & 3)) << 3)] = *(uint4*)u;
        }
    };
    auto stageB = [&](int k0, ushort* Bs) {
#pragma unroll
        for (int it = 0; it < 2; it++) {
            int r0 = wave * 32 + it * 16;                        // wave-uniform LDS dest
            const ushort* g = &W1b[(long)(r0 + (lane >> 2)) * F_IN + k0 + (lane & 3) * 8];
            gload_lds16(g, &Bs[r0 * 32]);
        }
    };

    // ---- phase A: acc = x @ W1^T (K=256) ----
    f32x4 acc[4][4] = {};
    loadX(0);
    stageB(0, smem + 4096);
    writeA(smem);
    __syncthreads();
    for (int k0 = 0; k0 < F_IN; k0 += 32) {
        const int cur = (k0 >> 5) & 1;
        ushort* As = smem + cur * 8192;
        ushort* Bs = As + 4096;
        const bool more = (k0 + 32 < F_IN);
        if (more) {
            stageB(k0 + 32, smem + (cur ^ 1) * 8192 + 4096);
            loadX(k0 + 32);
        }
        bf16x8 af[4], bfr[4];
#pragma unroll
        for (int t4 = 0; t4 < 4; t4++) {
            int ra = wm + t4 * 16 + lr;
            int rb = wn + t4 * 16 + lr;
            af[t4]  = *(bf16x8*)&As[ra * 32 + ((lq ^ ((ra >> 1) & 3)) << 3)];
            bfr[t4] = *(bf16x8*)&Bs[rb * 32 + ((lq ^ ((rb >> 1) & 3)) << 3)];
        }
#pragma unroll
        for (int i = 0; i < 4; i++)
#pragma unroll
            for (int j = 0; j < 4; j++)
                acc[i][j] = __builtin_amdgcn_mfma_f32_16x16x32_bf16(af[i], bfr[j], acc[i][j], 0, 0, 0);
        if (more) writeA(smem + (cur ^ 1) * 8192);
        __syncthreads();
    }

    // prefetch W2 frags for k0=0
    uint4 wb[2][4];
#pragma unroll
    for (int t4 = 0; t4 < 4; t4++)
        wb[0][t4] = *(const uint4*)&W2b[(long)(wn + t4 * 16 + lr) * CCH + lq * 8];

    // ---- epilogue A: h = relu(acc + b1) -> Ht (swizzled) ----
    {
        float bv[4];
#pragma unroll
        for (int j = 0; j < 4; j++) bv[j] = b1[wn + j * 16 + lr];
#pragma unroll
        for (int i = 0; i < 4; i++)
#pragma unroll
            for (int r = 0; r < 4; r++) {
                int row = wm + i * 16 + lq * 4 + r;
                int rx  = (row & 7) << 3;
#pragma unroll
                for (int j = 0; j < 4; j++)
                    Ht[row * 128 + ((wn + j * 16 + lr) ^ rx)] = f2bf(fmaxf(acc[i][j][r] + bv[j], 0.f));
            }
    }
    __syncthreads();

    // ---- phase B: acc2 = h @ W2^T (K=128), barrier-free ----
    f32x4 acc2[4][4] = {};
#pragma unroll
    for (int kk = 0; kk < 4; kk++) {
        const int k0 = kk * 32;
        if (kk < 3) {
#pragma unroll
            for (int t4 = 0; t4 < 4; t4++)
                wb[(kk + 1) & 1][t4] =
                    *(const uint4*)&W2b[(long)(wn + t4 * 16 + lr) * CCH + k0 + 32 + lq * 8];
        }
        bf16x8 af[4];
#pragma unroll
        for (int t4 = 0; t4 < 4; t4++) {
            int ra = wm + t4 * 16 + lr;
            af[t4] = *(bf16x8*)&Ht[ra * 128 + ((k0 + lq * 8) ^ ((ra & 7) << 3))];
        }
#pragma unroll
        for (int i = 0; i < 4; i++)
#pragma unroll
            for (int j = 0; j < 4; j++)
                acc2[i][j] = __builtin_amdgcn_mfma_f32_16x16x32_bf16(af[i], *(bf16x8*)&wb[kk & 1][j],
                                                                     acc2[i][j], 0, 0, 0);
    }
    __syncthreads();

    // ---- epilogue B: z -> Ht (swizzled) -> coalesced store ----
#pragma unroll
    for (int i = 0; i < 4; i++)
#pragma unroll
        for (int r = 0; r < 4; r++) {
            int row = wm + i * 16 + lq * 4 + r;
            int rx  = (row & 7) << 3;
#pragma unroll
            for (int j = 0; j < 4; j++)
                Ht[row * 128 + ((wn + j * 16 + lr) ^ rx)] = f2bf(acc2[i][j][r]);
        }
    __syncthreads();
    {
        int colq = tid & 15, row0 = tid >> 4;
#pragma unroll
        for (int i = 0; i < 8; i++) {
            int row = row0 + i * 16;
            if (m0 + row < M)
                *(uint4*)&Zq[(long)(m0 + row) * CCH + colq * 8] =
                    *(uint4*)&Ht[row * 128 + ((colq * 8) ^ ((row & 7) << 3))];
        }
    }
}

// ---------------- U0: histogram (FIRST) ∪ gemm quarter A ----------------
__global__ __launch_bounds__(256)
void u_hist_gemm(const int* __restrict__ dst, int* __restrict__ histC, int* __restrict__ histT,
                 int E, int ncp, int nchunks,
                 const float* __restrict__ X, const ushort* __restrict__ W1b,
                 const ushort* __restrict__ W2b, const float* __restrict__ b1,
                 ushort* __restrict__ Zq, int M)
{
    __shared__ unsigned smem4[8192];    // 32 KB, carved per path
    const int bid = blockIdx.x;
    if (bid < nchunks)
        hist_body(smem4, dst, histC, histT, E, ncp, bid);
    else
        gemm_body(smem4, X, W1b, W2b, b1, Zq, M, (bid - nchunks) * 128);
}

// ---------------- U1: partition (XCD-contiguous chunk remap, FIRST) ∪ gemm part B ----------------
__global__ __launch_bounds__(256)
void u_part_gemm(const int* __restrict__ src, const int* __restrict__ dst,
                 const int* __restrict__ histC, const int* __restrict__ histPre,
                 const int* __restrict__ btot, int* __restrict__ gbase,
                 unsigned* __restrict__ pairs, int E, int ncp, int nchunks, int ngA,
                 const float* __restrict__ X, const ushort* __restrict__ W1b,
                 const ushort* __restrict__ W2b, const float* __restrict__ b1,
                 ushort* __restrict__ Zq, int M)
{
    __shared__ unsigned smem4[8192];
    const int bid = blockIdx.x;
    if (bid < nchunks) {
        const int x = bid & 7, i = bid >> 3;
        const int q = nchunks >> 3, r = nchunks & 7;
        const int chunk = (x < r) ? x * (q + 1) + i : r * (q + 1) + (x - r) * q + i;
        partition_body(smem4, src, dst, histC, histPre, btot, gbase, pairs, E, ncp, chunk);
    } else {
        gemm_body(smem4, X, W1b, W2b, b1, Zq, M, (ngA + bid - nchunks) * 128);
    }
}

// ---------------- U2: bucket CSR (FIRST) ∪ gemm part C ----------------
__global__ __launch_bounds__(256)
void u_csr_gemm(const unsigned* __restrict__ pairs, const int* __restrict__ base,
                int* __restrict__ row_start, float* __restrict__ dinv,
                unsigned* __restrict__ csr, int N, int E, int nbuck, int ngAB,
                const float* __restrict__ X, const ushort* __restrict__ W1b,
                const ushort* __restrict__ W2b, const float* __restrict__ b1,
                ushort* __restrict__ Zq, int M)
{
    __shared__ unsigned smem4[8192];
    const int bid = blockIdx.x;
    if (bid < nbuck)
        csr_body(smem4, pairs, base, row_start, dinv, csr, N, E, bid, nbuck - 1);
    else
        gemm_body(smem4, X, W1b, W2b, b1, Zq, M, (ngAB + bid - nbuck) * 128);
}

// ---------------- K6: gather (R7-proven 8-deep; R8's 16-deep hit occupancy cliff
//                  VGPR 32->56, occ 68->36, dur 80->109 — reverted) ----------------
__global__ __launch_bounds__(256)
void gather_nodes(const unsigned* __restrict__ zq, const unsigned* __restrict__ csr,
                  const int* __restrict__ row_start, const float* __restrict__ dinv,
                  const float* __restrict__ b2, float* __restrict__ out, int N)
{
    const int node = blockIdx.x * 4 + (threadIdx.x >> 6);
    const int lane = threadIdx.x & 63;
    if (node >= N) return;

    const float di = dinv[node];
    float2 zs = bf2f2(zq[(long)node * 64 + lane]);
    float acc0 = di * zs.x, acc1 = di * zs.y;      // self-loop: dinv[d]*z[d]

    const int rs = row_start[node];
    const int re = row_start[node + 1];
    int j = rs;
    for (; j + 8 <= re; j += 8) {
        unsigned sI[8], zv[8];
        float dv[8];
#pragma unroll
        for (int q = 0; q < 8; q++) sI[q] = csr[j + q];
#pragma unroll
        for (int q = 0; q < 8; q++) dv[q] = dinv[sI[q]];
#pragma unroll
        for (int q = 0; q < 8; q++) zv[q] = zq[(long)sI[q] * 64 + lane];
#pragma unroll
        for (int q = 0; q < 8; q++) { float2 f = bf2f2(zv[q]); acc0 += dv[q] * f.x; acc1 += dv[q] * f.y; }
    }
    for (; j < re; j++) {
        unsigned s = csr[j];
        float ds = dinv[s];
        float2 f = bf2f2(zq[(long)s * 64 + lane]);
        acc0 += ds * f.x; acc1 += ds * f.y;
    }

    float2 o;
    o.x = b2[lane * 2 + 0] + di * acc0;
    o.y = b2[lane * 2 + 1] + di * acc1;
    *(float2*)&out[(long)node * CCH + lane * 2] = o;
}

extern "C" void kernel_launch(void* const* d_in, const int* in_sizes, int n_in,
                              void* d_out, int out_size, void* d_ws, size_t ws_size,
                              hipStream_t stream)
{
    const float* x  = (const float*)d_in[0];
    const int*   ei = (const int*)d_in[1];
    const float* W1 = (const float*)d_in[2];
    const float* b1 = (const float*)d_in[3];
    const float* W2 = (const float*)d_in[4];
    const float* b2 = (const float*)d_in[5];
    float* out = (float*)d_out;

    const int N = in_sizes[0] / F_IN;
    const int E = in_sizes[1] / 2;
    const int* src = ei;
    const int* dst = ei + E;

    const int nchunks = (E + CHUNK - 1) / CHUNK;        // 782
    const int ncp     = (nchunks + 63) & ~63;           // 832
    const int nbuck   = (N + BNODES - 1) / BNODES;      // 782
    const int ngrid   = (N + 127) / 128;                // 782
    // gemm split sized to build partners (hist:part:csr ~ 28:60:40) -> 25% / 45% / 30%
    const int ngA     = ngrid / 4;                      // 195 (with hist)
    const int ngB     = (ngrid * 9) / 20;               // 351 (with partition)
    const int ngC     = ngrid - ngA - ngB;              // 236 (with csr)
    const int ncvt    = (CCH * F_IN + CCH * CCH + 255) / 256;

    char* ws = (char*)d_ws;
    ushort* zq    = (ushort*)ws;   ws += (size_t)N * CCH * 2;
    ushort* w1b   = (ushort*)ws;   ws += (size_t)CCH * F_IN * 2;
    ushort* w2b   = (ushort*)ws;   ws += (size_t)CCH * CCH * 2;
    unsigned* prs = (unsigned*)ws; ws += (size_t)E * 4;
    unsigned* csr = (unsigned*)ws; ws += (size_t)E * 4;
    int* rstart   = (int*)ws;      ws += ((size_t)N + 1) * 4;
    float* dinv   = (float*)ws;    ws += (size_t)N * 4;
    int* histC    = (int*)ws;      ws += (size_t)nchunks * NBUCK * 4;
    int* histT    = (int*)ws;      ws += (size_t)NBUCK * ncp * 4;
    int* btot     = (int*)ws;      ws += NBUCK * 4;
    int* gbase    = (int*)ws;      ws += (NBUCK + 1) * 4;

    // K0: weight cvt (tiny, serial — U0's gemm needs w1b)
    cvt_w<<<ncvt, 256, 0, stream>>>(W1, W2, w1b, w2b);
    // U0: histogram (first) ∪ gemm part A
    u_hist_gemm<<<nchunks + ngA, 256, 0, stream>>>(dst, histC, histT, E, ncp, nchunks,
                                                   x, w1b, w2b, b1, zq, N);
    // K2: bucket prefix IN PLACE in tiled histT
    scan_buckets<<<NBUCK / 16, 1024, 0, stream>>>(histT, btot, nchunks, ncp);
    // U1: partition (XCD-remapped, first) ∪ gemm part B
    u_part_gemm<<<nchunks + ngB, 256, 0, stream>>>(src, dst, histC, histT, btot, gbase, prs,
                                                   E, ncp, nchunks, ngA, x, w1b, w2b, b1, zq, N);
    // U2: bucket-CSR (first) ∪ gemm part C
    u_csr_gemm<<<nbuck + ngC, 256, 0, stream>>>(prs, gbase, rstart, dinv, csr, N, E,
                                                nbuck, ngA + ngB, x, w1b, w2b, b1, zq, N);
    // K6: aggregate (applies dinv[src] * dinv[dst])
    gather_nodes<<<(N + 3) / 4, 256, 0, stream>>>((const unsigned*)zq, csr, rstart, dinv, b2, out, N);
}

// Round 10
// 308.129 us; speedup vs baseline: 1.1188x; 1.0790x over previous
//
#include <hip/hip_runtime.h>

typedef unsigned short ushort;
typedef __bf16 bf16x8 __attribute__((ext_vector_type(8)));
typedef float f32x4 __attribute__((ext_vector_type(4)));

#define F_IN 256
#define CCH  128
#define BSH  7
#define BNODES 128
#define NBUCK 1024
#define CHUNK 2048

// ---------------- helpers ----------------
__device__ __forceinline__ ushort f2bf(float f) {
    union { float f; unsigned i; } u; u.f = f;
    unsigned r = u.i + 0x7fffu + ((u.i >> 16) & 1u);   // RNE
    return (ushort)(r >> 16);
}
__device__ __forceinline__ float2 bf2f2(unsigned u) {
    union { unsigned i; float f; } lo, hi;
    lo.i = u << 16;
    hi.i = u & 0xffff0000u;
    return make_float2(lo.f, hi.f);
}
__device__ __forceinline__ void gload_lds16(const void* g, void* l) {
    __builtin_amdgcn_global_load_lds((const __attribute__((address_space(1))) unsigned*)g,
                                     (__attribute__((address_space(3))) unsigned*)l, 16, 0, 0);
}

// ---------------- K1: per-chunk histogram (tiled histT) + weight cvt ----------------
// histT TILED: [(b>>4)][chunk][b&15] -> each 64B line = 16 buckets of ONE chunk (R7-proven).
// w1b PRE-SWIZZLED: within each 32-col k-tile, chunk c -> c ^ ((row>>1)&3).
__global__ __launch_bounds__(256)
void hist_cvt(const int* __restrict__ dst, int* __restrict__ histC, int* __restrict__ histT,
              int E, int nchunks, int ncp,
              const float* __restrict__ W1, const float* __restrict__ W2,
              ushort* __restrict__ w1b, ushort* __restrict__ w2b)
{
    const int blk = blockIdx.x, t = threadIdx.x;
    if (blk >= nchunks) {
        int i = (blk - nchunks) * 256 + t;
        if (i < CCH * F_IN) {
            int c  = i & 31;
            int cs = c ^ (((i >> 9) & 3) << 3);        // (row>>1)&3, row = i>>8
            w1b[(i & ~31) | cs] = f2bf(W1[i]);
        } else {
            int j = i - CCH * F_IN;
            if (j < CCH * CCH) w2b[j] = f2bf(W2[j]);
        }
        return;
    }
    __shared__ int h[NBUCK];
    for (int i = t; i < NBUCK; i += 256) h[i] = 0;
    __syncthreads();
    int cb = blk * CHUNK, ce = min(cb + CHUNK, E);
    for (int e = cb + t; e < ce; e += 256)
        atomicAdd(&h[dst[e] >> BSH], 1);
    __syncthreads();
    const int ncp16 = ncp * 16;
    for (int i = t; i < NBUCK; i += 256) {
        int v = h[i];
        histC[blk * NBUCK + i] = v;                            // chunk-major (partition scan 1)
        histT[(i >> 4) * ncp16 + blk * 16 + (i & 15)] = v;     // tiled (scan / partition scan 2)
    }
}

// ---------------- K2: per-bucket cross-chunk prefix, IN PLACE in tiled histT ----------------
__global__ __launch_bounds__(1024)
void scan_buckets(int* __restrict__ histT, int* __restrict__ btot, int nchunks, int ncp)
{
    const int w = threadIdx.x >> 6;                 // 0..15 = bucket within tile
    const int b = blockIdx.x * 16 + w;
    const int lane = threadIdx.x & 63;
    const int tb = blockIdx.x * (ncp * 16) + w;
    int carry = 0;
    for (int c = 0; c < nchunks; c += 64) {
        int idx = c + lane;
        int v = (idx < nchunks) ? histT[tb + idx * 16] : 0;
        int inc = v;
#pragma unroll
        for (int off = 1; off < 64; off <<= 1) {
            int x = __shfl_up(inc, off, 64);
            if (lane >= off) inc += x;
        }
        if (idx < nchunks) histT[tb + idx * 16] = carry + inc - v;   // exclusive prefix in place
        carry += __shfl(inc, 63, 64);
    }
    if (lane == 0) btot[b] = carry;
}

// ---------------- device body: partition (shuffle scans, direct write; R8-verified) ----------------
__device__ __forceinline__ void partition_body(unsigned* smem4,
    const int* __restrict__ src, const int* __restrict__ dst,
    const int* __restrict__ histC, const int* __restrict__ histPre,
    const int* __restrict__ btot, int* __restrict__ gbase,
    unsigned* __restrict__ pairs, int E, int ncp, int blk)
{
    int* lcur = (int*)smem4;               // NBUCK
    int* off  = lcur + NBUCK;              // NBUCK: global_base - lbase
    int* wsum = off + NBUCK;               // 4
    const int t = threadIdx.x;
    const int wv = t >> 6, lane = t & 63;

    // ---- scan 1: this chunk's hist -> lbase (regs) / lcur ----
    int4 cv = *(const int4*)&histC[blk * NBUCK + 4 * t];
    int tsum = cv.x + cv.y + cv.z + cv.w;
    int inc = tsum;
#pragma unroll
    for (int o = 1; o < 64; o <<= 1) {
        int x = __shfl_up(inc, o, 64);
        if (lane >= o) inc += x;
    }
    if (lane == 63) wsum[wv] = inc;
    __syncthreads();
    int woff = 0;
    if (wv > 0) woff += wsum[0];
    if (wv > 1) woff += wsum[1];
    if (wv > 2) woff += wsum[2];
    int l0 = woff + inc - tsum, l1 = l0 + cv.x, l2 = l1 + cv.y, l3 = l2 + cv.z;
    lcur[4 * t] = l0; lcur[4 * t + 1] = l1; lcur[4 * t + 2] = l2; lcur[4 * t + 3] = l3;

    // ---- scan 2: bucket totals -> global bases; off = base + pref - lbase ----
    int4 bt = *(const int4*)&btot[4 * t];
    int bsum = bt.x + bt.y + bt.z + bt.w;
    int binc = bsum;
#pragma unroll
    for (int o = 1; o < 64; o <<= 1) {
        int x = __shfl_up(binc, o, 64);
        if (lane >= o) binc += x;
    }
    __syncthreads();                        // wsum reuse safe
    if (lane == 63) wsum[wv] = binc;
    __syncthreads();
    int bwoff = 0;
    if (wv > 0) bwoff += wsum[0];
    if (wv > 1) bwoff += wsum[1];
    if (wv > 2) bwoff += wsum[2];
    int b0 = bwoff + binc - bsum, b1 = b0 + bt.x, b2 = b1 + bt.y, b3 = b2 + bt.z;
    if (blk == 0) {
        *(int4*)&gbase[4 * t] = make_int4(b0, b1, b2, b3);
        if (t == 255) gbase[NBUCK] = b3 + bt.w;
    }
    // tiled per-chunk prefix (in-place scanned histT): rows 4t..4t+3, col blk -> one int4
    int4 pf = *(const int4*)&histPre[(t >> 2) * (ncp * 16) + blk * 16 + (t & 3) * 4];
    off[4 * t]     = b0 + pf.x - l0;
    off[4 * t + 1] = b1 + pf.y - l1;
    off[4 * t + 2] = b2 + pf.z - l2;
    off[4 * t + 3] = b3 + pf.w - l3;
    __syncthreads();

    // ---- single edge pass: direct write (locality via XCD-contiguous chunk remap) ----
    const int cb = blk * CHUNK, ce = min(cb + CHUNK, E);
    for (int e = cb + t; e < ce; e += 256) {
        int d = dst[e];
        int b = d >> BSH;
        unsigned packed = ((unsigned)src[e] << BSH) | (unsigned)(d & (BNODES - 1));
        int p = atomicAdd(&lcur[b], 1);
        pairs[off[b] + p] = packed;
    }
}

// ---------------- device body: per-bucket CSR finalize (shuffle scan; R8-verified) ----------------
__device__ __forceinline__ void csr_body(unsigned* smem4,
    const unsigned* __restrict__ pairs, const int* __restrict__ base,
    int* __restrict__ row_start, float* __restrict__ dinv,
    unsigned* __restrict__ csr, int N, int E, int b, int lastb)
{
    int* deg  = (int*)smem4;               // 128
    int* cur  = deg + BNODES;              // 128
    int* wsum = cur + BNODES;              // 2
    const int t = threadIdx.x;
    if (t < BNODES) deg[t] = 0;
    __syncthreads();
    const int rb = base[b], re = base[b + 1];
    for (int e = rb + t; e < re; e += 256)
        atomicAdd(&deg[pairs[e] & (BNODES - 1)], 1);
    __syncthreads();
    int v = (t < BNODES) ? deg[t] : 0;
    int inc = v;
#pragma unroll
    for (int o = 1; o < 64; o <<= 1) {
        int x = __shfl_up(inc, o, 64);
        if ((t & 63) >= o) inc += x;
    }
    if (t < BNODES && (t & 63) == 63) wsum[t >> 6] = inc;
    __syncthreads();
    const int n0 = b << BSH;
    if (t < BNODES) {
        int excl = inc - v + ((t >= 64) ? wsum[0] : 0);
        cur[t] = rb + excl;
        if (n0 + t < N) {
            row_start[n0 + t] = rb + excl;
            dinv[n0 + t] = rsqrtf((float)v + 1.0f);
        }
    }
    if (b == lastb && t == 0) row_start[N] = E;
    __syncthreads();
    for (int e = rb + t; e < re; e += 256) {
        unsigned p = pairs[e];
        int slot = atomicAdd(&cur[p & (BNODES - 1)], 1);
        csr[slot] = p >> BSH;
    }
}

// ---------------- device body: fused GEMM  zq = relu(x@W1^T+b1) @ W2^T ----------------
// [R3 PMC: bank conflicts 3.08M->200K (swizzles verified). VGPR uncapped (R2 spill lesson).
//  dinv applied in gather. Row clamp (R6-proven).]
__device__ __forceinline__ void gemm_body(unsigned* smem4,
    const float* __restrict__ X, const ushort* __restrict__ W1b,
    const ushort* __restrict__ W2b, const float* __restrict__ b1,
    ushort* __restrict__ Zq, int M, int m0)
{
    ushort* smem = (ushort*)smem4;          // 32768 B: dbuf k-tiles, aliased by Ht[128][128]
    ushort* Ht = smem;
    const int tid  = threadIdx.x;
    const int wave = tid >> 6, lane = tid & 63;
    const int wm = (wave & 1) * 64, wn = (wave >> 1) * 64;
    const int lr = lane & 15, lq = lane >> 4;

    const int arow = tid >> 2;
    const int aq   = tid & 3;

    float4 ar[2][2];
    auto loadX = [&](int k0) {
#pragma unroll
        for (int it = 0; it < 2; it++) {
            int grow = min(m0 + arow + it * 64, M - 1);        // clamp, no branch
            const float* p = &X[(long)grow * F_IN + k0 + aq * 8];
            ar[it][0] = *(const float4*)p;
            ar[it][1] = *(const float4*)(p + 4);
        }
    };
    auto writeA = [&](ushort* As) {
#pragma unroll
        for (int it = 0; it < 2; it++) {
            int row = arow + it * 64;
            ushort u[8] = { f2bf(ar[it][0].x), f2bf(ar[it][0].y), f2bf(ar[it][0].z), f2bf(ar[it][0].w),
                            f2bf(ar[it][1].x), f2bf(ar[it][1].y), f2bf(ar[it][1].z), f2bf(ar[it][1].w) };
            *(uint4*)&As[row * 32 + ((aq ^ ((row >> 1) & 3)) << 3)] = *(uint4*)u;
        }
    };
    auto stageB = [&](int k0, ushort* Bs) {
#pragma unroll
        for (int it = 0; it < 2; it++) {
            int r0 = wave * 32 + it * 16;                        // wave-uniform LDS dest
            const ushort* g = &W1b[(long)(r0 + (lane >> 2)) * F_IN + k0 + (lane & 3) * 8];
            gload_lds16(g, &Bs[r0 * 32]);
        }
    };

    // ---- phase A: acc = x @ W1^T (K=256) ----
    f32x4 acc[4][4] = {};
    loadX(0);
    stageB(0, smem + 4096);
    writeA(smem);
    __syncthreads();
    for (int k0 = 0; k0 < F_IN; k0 += 32) {
        const int cur = (k0 >> 5) & 1;
        ushort* As = smem + cur * 8192;
        ushort* Bs = As + 4096;
        const bool more = (k0 + 32 < F_IN);
        if (more) {
            stageB(k0 + 32, smem + (cur ^ 1) * 8192 + 4096);
            loadX(k0 + 32);
        }
        bf16x8 af[4], bfr[4];
#pragma unroll
        for (int t4 = 0; t4 < 4; t4++) {
            int ra = wm + t4 * 16 + lr;
            int rb = wn + t4 * 16 + lr;
            af[t4]  = *(bf16x8*)&As[ra * 32 + ((lq ^ ((ra >> 1) & 3)) << 3)];
            bfr[t4] = *(bf16x8*)&Bs[rb * 32 + ((lq ^ ((rb >> 1) & 3)) << 3)];
        }
#pragma unroll
        for (int i = 0; i < 4; i++)
#pragma unroll
            for (int j = 0; j < 4; j++)
                acc[i][j] = __builtin_amdgcn_mfma_f32_16x16x32_bf16(af[i], bfr[j], acc[i][j], 0, 0, 0);
        if (more) writeA(smem + (cur ^ 1) * 8192);
        __syncthreads();
    }

    // prefetch W2 frags for k0=0
    uint4 wb[2][4];
#pragma unroll
    for (int t4 = 0; t4 < 4; t4++)
        wb[0][t4] = *(const uint4*)&W2b[(long)(wn + t4 * 16 + lr) * CCH + lq * 8];

    // ---- epilogue A: h = relu(acc + b1) -> Ht (swizzled) ----
    {
        float bv[4];
#pragma unroll
        for (int j = 0; j < 4; j++) bv[j] = b1[wn + j * 16 + lr];
#pragma unroll
        for (int i = 0; i < 4; i++)
#pragma unroll
            for (int r = 0; r < 4; r++) {
                int row = wm + i * 16 + lq * 4 + r;
                int rx  = (row & 7) << 3;
#pragma unroll
                for (int j = 0; j < 4; j++)
                    Ht[row * 128 + ((wn + j * 16 + lr) ^ rx)] = f2bf(fmaxf(acc[i][j][r] + bv[j], 0.f));
            }
    }
    __syncthreads();

    // ---- phase B: acc2 = h @ W2^T (K=128), barrier-free ----
    f32x4 acc2[4][4] = {};
#pragma unroll
    for (int kk = 0; kk < 4; kk++) {
        const int k0 = kk * 32;
        if (kk < 3) {
#pragma unroll
            for (int t4 = 0; t4 < 4; t4++)
                wb[(kk + 1) & 1][t4] =
                    *(const uint4*)&W2b[(long)(wn + t4 * 16 + lr) * CCH + k0 + 32 + lq * 8];
        }
        bf16x8 af[4];
#pragma unroll
        for (int t4 = 0; t4 < 4; t4++) {
            int ra = wm + t4 * 16 + lr;
            af[t4] = *(bf16x8*)&Ht[ra * 128 + ((k0 + lq * 8) ^ ((ra & 7) << 3))];
        }
#pragma unroll
        for (int i = 0; i < 4; i++)
#pragma unroll
            for (int j = 0; j < 4; j++)
                acc2[i][j] = __builtin_amdgcn_mfma_f32_16x16x32_bf16(af[i], *(bf16x8*)&wb[kk & 1][j],
                                                                     acc2[i][j], 0, 0, 0);
    }
    __syncthreads();

    // ---- epilogue B: z -> Ht (swizzled) -> coalesced store ----
#pragma unroll
    for (int i = 0; i < 4; i++)
#pragma unroll
        for (int r = 0; r < 4; r++) {
            int row = wm + i * 16 + lq * 4 + r;
            int rx  = (row & 7) << 3;
#pragma unroll
            for (int j = 0; j < 4; j++)
                Ht[row * 128 + ((wn + j * 16 + lr) ^ rx)] = f2bf(acc2[i][j][r]);
        }
    __syncthreads();
    {
        int colq = tid & 15, row0 = tid >> 4;
#pragma unroll
        for (int i = 0; i < 8; i++) {
            int row = row0 + i * 16;
            if (m0 + row < M)
                *(uint4*)&Zq[(long)(m0 + row) * CCH + colq * 8] =
                    *(uint4*)&Ht[row * 128 + ((colq * 8) ^ ((row & 7) << 3))];
        }
    }
}

// ---------------- U1: partition (XCD-contiguous chunk remap, FIRST) ∪ gemm half A ----------------
__global__ __launch_bounds__(256)
void u_part_gemm(const int* __restrict__ src, const int* __restrict__ dst,
                 const int* __restrict__ histC, const int* __restrict__ histPre,
                 const int* __restrict__ btot, int* __restrict__ gbase,
                 unsigned* __restrict__ pairs, int E, int ncp, int nchunks,
                 const float* __restrict__ X, const ushort* __restrict__ W1b,
                 const ushort* __restrict__ W2b, const float* __restrict__ b1,
                 ushort* __restrict__ Zq, int M)
{
    __shared__ unsigned smem4[8192];    // 32 KB, carved per path
    const int bid = blockIdx.x;
    if (bid < nchunks) {
        const int x = bid & 7, i = bid >> 3;
        const int q = nchunks >> 3, r = nchunks & 7;
        const int chunk = (x < r) ? x * (q + 1) + i : r * (q + 1) + (x - r) * q + i;
        partition_body(smem4, src, dst, histC, histPre, btot, gbase, pairs, E, ncp, chunk);
    } else {
        gemm_body(smem4, X, W1b, W2b, b1, Zq, M, (bid - nchunks) * 128);
    }
}

// ---------------- U2: bucket CSR (FIRST) ∪ gemm half B ----------------
__global__ __launch_bounds__(256)
void u_csr_gemm(const unsigned* __restrict__ pairs, const int* __restrict__ base,
                int* __restrict__ row_start, float* __restrict__ dinv,
                unsigned* __restrict__ csr, int N, int E, int nbuck, int ngA,
                const float* __restrict__ X, const ushort* __restrict__ W1b,
                const ushort* __restrict__ W2b, const float* __restrict__ b1,
                ushort* __restrict__ Zq, int M)
{
    __shared__ unsigned smem4[8192];
    const int bid = blockIdx.x;
    if (bid < nbuck)
        csr_body(smem4, pairs, base, row_start, dinv, csr, N, E, bid, nbuck - 1);
    else
        gemm_body(smem4, X, W1b, W2b, b1, Zq, M, (ngA + bid - nbuck) * 128);
}

// ---------------- K6: gather — constant 8-deep batches with MASKED tail ----------------
// [R8 lesson: 16-deep dropped half the nodes onto a 4-wide path -> avg MLP fell, 80->109us.
//  The real cost was the serial 1-wide tail (~4 dependent ~400cy iterations/node). Fix: every
//  batch is 8-deep with clamped indices (csr[min(j+q,re-1)]) and dv masked to 0 for q past
//  the end — MLP stays 8 for the entire row, no serial chain, VGPR ~36 (<64 => 8 waves/SIMD).]
__global__ __launch_bounds__(256)
void gather_nodes(const unsigned* __restrict__ zq, const unsigned* __restrict__ csr,
                  const int* __restrict__ row_start, const float* __restrict__ dinv,
                  const float* __restrict__ b2, float* __restrict__ out, int N)
{
    const int node = blockIdx.x * 4 + (threadIdx.x >> 6);
    const int lane = threadIdx.x & 63;
    if (node >= N) return;

    const float di = dinv[node];
    float2 zs = bf2f2(zq[(long)node * 64 + lane]);
    float acc0 = di * zs.x, acc1 = di * zs.y;      // self-loop: dinv[d]*z[d]

    const int rs = row_start[node];
    const int re = row_start[node + 1];
    for (int j = rs; j < re; j += 8) {
        unsigned sI[8], zv[8];
        float dv[8];
#pragma unroll
        for (int q = 0; q < 8; q++) sI[q] = csr[min(j + q, re - 1)];   // clamped: always in-bounds
#pragma unroll
        for (int q = 0; q < 8; q++) zv[q] = zq[(long)sI[q] * 64 + lane];
#pragma unroll
        for (int q = 0; q < 8; q++) dv[q] = (j + q < re) ? dinv[sI[q]] : 0.f;  // mask via weight
#pragma unroll
        for (int q = 0; q < 8; q++) { float2 f = bf2f2(zv[q]); acc0 += dv[q] * f.x; acc1 += dv[q] * f.y; }
    }

    float2 o;
    o.x = b2[lane * 2 + 0] + di * acc0;
    o.y = b2[lane * 2 + 1] + di * acc1;
    *(float2*)&out[(long)node * CCH + lane * 2] = o;
}

extern "C" void kernel_launch(void* const* d_in, const int* in_sizes, int n_in,
                              void* d_out, int out_size, void* d_ws, size_t ws_size,
                              hipStream_t stream)
{
    const float* x  = (const float*)d_in[0];
    const int*   ei = (const int*)d_in[1];
    const float* W1 = (const float*)d_in[2];
    const float* b1 = (const float*)d_in[3];
    const float* W2 = (const float*)d_in[4];
    const float* b2 = (const float*)d_in[5];
    float* out = (float*)d_out;

    const int N = in_sizes[0] / F_IN;
    const int E = in_sizes[1] / 2;
    const int* src = ei;
    const int* dst = ei + E;

    const int nchunks = (E + CHUNK - 1) / CHUNK;        // 782
    const int ncp     = (nchunks + 63) & ~63;           // 832
    const int nbuck   = (N + BNODES - 1) / BNODES;      // 782
    const int ngrid   = (N + 127) / 128;                // 782
    const int ngA     = (ngrid + 1) / 2;                // 391 (gemm half A)
    const int ngB     = ngrid - ngA;                    // 391 (gemm half B)
    const int ncvt    = (CCH * F_IN + CCH * CCH + 255) / 256;

    char* ws = (char*)d_ws;
    ushort* zq    = (ushort*)ws;   ws += (size_t)N * CCH * 2;
    ushort* w1b   = (ushort*)ws;   ws += (size_t)CCH * F_IN * 2;
    ushort* w2b   = (ushort*)ws;   ws += (size_t)CCH * CCH * 2;
    unsigned* prs = (unsigned*)ws; ws += (size_t)E * 4;
    unsigned* csr = (unsigned*)ws; ws += (size_t)E * 4;
    int* rstart   = (int*)ws;      ws += ((size_t)N + 1) * 4;
    float* dinv   = (float*)ws;    ws += (size_t)N * 4;
    int* histC    = (int*)ws;      ws += (size_t)nchunks * NBUCK * 4;
    int* histT    = (int*)ws;      ws += (size_t)NBUCK * ncp * 4;
    int* btot     = (int*)ws;      ws += NBUCK * 4;
    int* gbase    = (int*)ws;      ws += (NBUCK + 1) * 4;

    // K1: histogram (tiled histT) + weight cvt
    hist_cvt<<<nchunks + ncvt, 256, 0, stream>>>(dst, histC, histT, E, nchunks, ncp, W1, W2, w1b, w2b);
    // K2: bucket prefix IN PLACE in tiled histT
    scan_buckets<<<NBUCK / 16, 1024, 0, stream>>>(histT, btot, nchunks, ncp);
    // U1: partition (XCD-remapped, first) ∪ gemm-half-A
    u_part_gemm<<<nchunks + ngA, 256, 0, stream>>>(src, dst, histC, histT, btot, gbase, prs,
                                                   E, ncp, nchunks, x, w1b, w2b, b1, zq, N);
    // U2: bucket-CSR (first) ∪ gemm-half-B
    u_csr_gemm<<<nbuck + ngB, 256, 0, stream>>>(prs, gbase, rstart, dinv, csr, N, E,
                                                nbuck, ngA, x, w1b, w2b, b1, zq, N);
    // K6: aggregate (applies dinv[src] * dinv[dst])
    gather_nodes<<<(N + 3) / 4, 256, 0, stream>>>((const unsigned*)zq, csr, rstart, dinv, b2, out, N);
}

// Round 11
// 304.492 us; speedup vs baseline: 1.1321x; 1.0119x over previous
//
#include <hip/hip_runtime.h>

typedef unsigned short ushort;
typedef __bf16 bf16x8 __attribute__((ext_vector_type(8)));
typedef float f32x4 __attribute__((ext_vector_type(4)));

#define F_IN 256
#define CCH  128
#define BSH  7
#define BNODES 128
#define NBUCK 1024
#define CHUNK 4096   // R11: 2048->4096 — halves per-chunk fixed costs (scans/setup) & hist traffic

// ---------------- helpers ----------------
__device__ __forceinline__ ushort f2bf(float f) {
    union { float f; unsigned i; } u; u.f = f;
    unsigned r = u.i + 0x7fffu + ((u.i >> 16) & 1u);   // RNE
    return (ushort)(r >> 16);
}
__device__ __forceinline__ float2 bf2f2(unsigned u) {
    union { unsigned i; float f; } lo, hi;
    lo.i = u << 16;
    hi.i = u & 0xffff0000u;
    return make_float2(lo.f, hi.f);
}
__device__ __forceinline__ void gload_lds16(const void* g, void* l) {
    __builtin_amdgcn_global_load_lds((const __attribute__((address_space(1))) unsigned*)g,
                                     (__attribute__((address_space(3))) unsigned*)l, 16, 0, 0);
}

// ---------------- K1: per-chunk histogram (tiled histT) + weight cvt ----------------
// histT TILED: [(b>>4)][chunk][b&15] -> each 64B line = 16 buckets of ONE chunk (R7-proven).
// w1b PRE-SWIZZLED: within each 32-col k-tile, chunk c -> c ^ ((row>>1)&3).
__global__ __launch_bounds__(256)
void hist_cvt(const int* __restrict__ dst, int* __restrict__ histC, int* __restrict__ histT,
              int E, int nchunks, int ncp,
              const float* __restrict__ W1, const float* __restrict__ W2,
              ushort* __restrict__ w1b, ushort* __restrict__ w2b)
{
    const int blk = blockIdx.x, t = threadIdx.x;
    if (blk >= nchunks) {
        int i = (blk - nchunks) * 256 + t;
        if (i < CCH * F_IN) {
            int c  = i & 31;
            int cs = c ^ (((i >> 9) & 3) << 3);        // (row>>1)&3, row = i>>8
            w1b[(i & ~31) | cs] = f2bf(W1[i]);
        } else {
            int j = i - CCH * F_IN;
            if (j < CCH * CCH) w2b[j] = f2bf(W2[j]);
        }
        return;
    }
    __shared__ int h[NBUCK];
    for (int i = t; i < NBUCK; i += 256) h[i] = 0;
    __syncthreads();
    int cb = blk * CHUNK, ce = min(cb + CHUNK, E);
    for (int e = cb + t; e < ce; e += 256)
        atomicAdd(&h[dst[e] >> BSH], 1);
    __syncthreads();
    const int ncp16 = ncp * 16;
    for (int i = t; i < NBUCK; i += 256) {
        int v = h[i];
        histC[blk * NBUCK + i] = v;                            // chunk-major (partition scan 1)
        histT[(i >> 4) * ncp16 + blk * 16 + (i & 15)] = v;     // tiled (scan / partition scan 2)
    }
}

// ---------------- K2: per-bucket cross-chunk prefix, IN PLACE in tiled histT ----------------
__global__ __launch_bounds__(1024)
void scan_buckets(int* __restrict__ histT, int* __restrict__ btot, int nchunks, int ncp)
{
    const int w = threadIdx.x >> 6;                 // 0..15 = bucket within tile
    const int b = blockIdx.x * 16 + w;
    const int lane = threadIdx.x & 63;
    const int tb = blockIdx.x * (ncp * 16) + w;
    int carry = 0;
    for (int c = 0; c < nchunks; c += 64) {
        int idx = c + lane;
        int v = (idx < nchunks) ? histT[tb + idx * 16] : 0;
        int inc = v;
#pragma unroll
        for (int off = 1; off < 64; off <<= 1) {
            int x = __shfl_up(inc, off, 64);
            if (lane >= off) inc += x;
        }
        if (idx < nchunks) histT[tb + idx * 16] = carry + inc - v;   // exclusive prefix in place
        carry += __shfl(inc, 63, 64);
    }
    if (lane == 0) btot[b] = carry;
}

// ---------------- device body: partition (shuffle scans, direct write; R8-verified) ----------------
__device__ __forceinline__ void partition_body(unsigned* smem4,
    const int* __restrict__ src, const int* __restrict__ dst,
    const int* __restrict__ histC, const int* __restrict__ histPre,
    const int* __restrict__ btot, int* __restrict__ gbase,
    unsigned* __restrict__ pairs, int E, int ncp, int blk)
{
    int* lcur = (int*)smem4;               // NBUCK
    int* off  = lcur + NBUCK;              // NBUCK: global_base - lbase
    int* wsum = off + NBUCK;               // 4
    const int t = threadIdx.x;
    const int wv = t >> 6, lane = t & 63;

    // ---- scan 1: this chunk's hist -> lbase (regs) / lcur ----
    int4 cv = *(const int4*)&histC[blk * NBUCK + 4 * t];
    int tsum = cv.x + cv.y + cv.z + cv.w;
    int inc = tsum;
#pragma unroll
    for (int o = 1; o < 64; o <<= 1) {
        int x = __shfl_up(inc, o, 64);
        if (lane >= o) inc += x;
    }
    if (lane == 63) wsum[wv] = inc;
    __syncthreads();
    int woff = 0;
    if (wv > 0) woff += wsum[0];
    if (wv > 1) woff += wsum[1];
    if (wv > 2) woff += wsum[2];
    int l0 = woff + inc - tsum, l1 = l0 + cv.x, l2 = l1 + cv.y, l3 = l2 + cv.z;
    lcur[4 * t] = l0; lcur[4 * t + 1] = l1; lcur[4 * t + 2] = l2; lcur[4 * t + 3] = l3;

    // ---- scan 2: bucket totals -> global bases; off = base + pref - lbase ----
    int4 bt = *(const int4*)&btot[4 * t];
    int bsum = bt.x + bt.y + bt.z + bt.w;
    int binc = bsum;
#pragma unroll
    for (int o = 1; o < 64; o <<= 1) {
        int x = __shfl_up(binc, o, 64);
        if (lane >= o) binc += x;
    }
    __syncthreads();                        // wsum reuse safe
    if (lane == 63) wsum[wv] = binc;
    __syncthreads();
    int bwoff = 0;
    if (wv > 0) bwoff += wsum[0];
    if (wv > 1) bwoff += wsum[1];
    if (wv > 2) bwoff += wsum[2];
    int b0 = bwoff + binc - bsum, b1 = b0 + bt.x, b2 = b1 + bt.y, b3 = b2 + bt.z;
    if (blk == 0) {
        *(int4*)&gbase[4 * t] = make_int4(b0, b1, b2, b3);
        if (t == 255) gbase[NBUCK] = b3 + bt.w;
    }
    // tiled per-chunk prefix (in-place scanned histT): rows 4t..4t+3, col blk -> one int4
    int4 pf = *(const int4*)&histPre[(t >> 2) * (ncp * 16) + blk * 16 + (t & 3) * 4];
    off[4 * t]     = b0 + pf.x - l0;
    off[4 * t + 1] = b1 + pf.y - l1;
    off[4 * t + 2] = b2 + pf.z - l2;
    off[4 * t + 3] = b3 + pf.w - l3;
    __syncthreads();

    // ---- single edge pass: direct write (locality via XCD-contiguous chunk remap) ----
    const int cb = blk * CHUNK, ce = min(cb + CHUNK, E);
    for (int e = cb + t; e < ce; e += 256) {
        int d = dst[e];
        int b = d >> BSH;
        unsigned packed = ((unsigned)src[e] << BSH) | (unsigned)(d & (BNODES - 1));
        int p = atomicAdd(&lcur[b], 1);
        pairs[off[b] + p] = packed;
    }
}

// ---------------- device body: per-bucket CSR finalize (shuffle scan; R8-verified) ----------------
__device__ __forceinline__ void csr_body(unsigned* smem4,
    const unsigned* __restrict__ pairs, const int* __restrict__ base,
    int* __restrict__ row_start, float* __restrict__ dinv,
    unsigned* __restrict__ csr, int N, int E, int b, int lastb)
{
    int* deg  = (int*)smem4;               // 128
    int* cur  = deg + BNODES;              // 128
    int* wsum = cur + BNODES;              // 2
    const int t = threadIdx.x;
    if (t < BNODES) deg[t] = 0;
    __syncthreads();
    const int rb = base[b], re = base[b + 1];
    for (int e = rb + t; e < re; e += 256)
        atomicAdd(&deg[pairs[e] & (BNODES - 1)], 1);
    __syncthreads();
    int v = (t < BNODES) ? deg[t] : 0;
    int inc = v;
#pragma unroll
    for (int o = 1; o < 64; o <<= 1) {
        int x = __shfl_up(inc, o, 64);
        if ((t & 63) >= o) inc += x;
    }
    if (t < BNODES && (t & 63) == 63) wsum[t >> 6] = inc;
    __syncthreads();
    const int n0 = b << BSH;
    if (t < BNODES) {
        int excl = inc - v + ((t >= 64) ? wsum[0] : 0);
        cur[t] = rb + excl;
        if (n0 + t < N) {
            row_start[n0 + t] = rb + excl;
            dinv[n0 + t] = rsqrtf((float)v + 1.0f);
        }
    }
    if (b == lastb && t == 0) row_start[N] = E;
    __syncthreads();
    for (int e = rb + t; e < re; e += 256) {
        unsigned p = pairs[e];
        int slot = atomicAdd(&cur[p & (BNODES - 1)], 1);
        csr[slot] = p >> BSH;
    }
}

// ---------------- device body: fused GEMM  zq = relu(x@W1^T+b1) @ W2^T ----------------
// [R3 PMC: bank conflicts 3.08M->200K (swizzles verified). VGPR uncapped (R2 spill lesson).
//  dinv applied in gather. Row clamp (R6-proven).]
__device__ __forceinline__ void gemm_body(unsigned* smem4,
    const float* __restrict__ X, const ushort* __restrict__ W1b,
    const ushort* __restrict__ W2b, const float* __restrict__ b1,
    ushort* __restrict__ Zq, int M, int m0)
{
    ushort* smem = (ushort*)smem4;          // 32768 B: dbuf k-tiles, aliased by Ht[128][128]
    ushort* Ht = smem;
    const int tid  = threadIdx.x;
    const int wave = tid >> 6, lane = tid & 63;
    const int wm = (wave & 1) * 64, wn = (wave >> 1) * 64;
    const int lr = lane & 15, lq = lane >> 4;

    const int arow = tid >> 2;
    const int aq   = tid & 3;

    float4 ar[2][2];
    auto loadX = [&](int k0) {
#pragma unroll
        for (int it = 0; it < 2; it++) {
            int grow = min(m0 + arow + it * 64, M - 1);        // clamp, no branch
            const float* p = &X[(long)grow * F_IN + k0 + aq * 8];
            ar[it][0] = *(const float4*)p;
            ar[it][1] = *(const float4*)(p + 4);
        }
    };
    auto writeA = [&](ushort* As) {
#pragma unroll
        for (int it = 0; it < 2; it++) {
            int row = arow + it * 64;
            ushort u[8] = { f2bf(ar[it][0].x), f2bf(ar[it][0].y), f2bf(ar[it][0].z), f2bf(ar[it][0].w),
                            f2bf(ar[it][1].x), f2bf(ar[it][1].y), f2bf(ar[it][1].z), f2bf(ar[it][1].w) };
            *(uint4*)&As[row * 32 + ((aq ^ ((row >> 1) & 3)) << 3)] = *(uint4*)u;
        }
    };
    auto stageB = [&](int k0, ushort* Bs) {
#pragma unroll
        for (int it = 0; it < 2; it++) {
            int r0 = wave * 32 + it * 16;                        // wave-uniform LDS dest
            const ushort* g = &W1b[(long)(r0 + (lane >> 2)) * F_IN + k0 + (lane & 3) * 8];
            gload_lds16(g, &Bs[r0 * 32]);
        }
    };

    // ---- phase A: acc = x @ W1^T (K=256) ----
    f32x4 acc[4][4] = {};
    loadX(0);
    stageB(0, smem + 4096);
    writeA(smem);
    __syncthreads();
    for (int k0 = 0; k0 < F_IN; k0 += 32) {
        const int cur = (k0 >> 5) & 1;
        ushort* As = smem + cur * 8192;
        ushort* Bs = As + 4096;
        const bool more = (k0 + 32 < F_IN);
        if (more) {
            stageB(k0 + 32, smem + (cur ^ 1) * 8192 + 4096);
            loadX(k0 + 32);
        }
        bf16x8 af[4], bfr[4];
#pragma unroll
        for (int t4 = 0; t4 < 4; t4++) {
            int ra = wm + t4 * 16 + lr;
            int rb = wn + t4 * 16 + lr;
            af[t4]  = *(bf16x8*)&As[ra * 32 + ((lq ^ ((ra >> 1) & 3)) << 3)];
            bfr[t4] = *(bf16x8*)&Bs[rb * 32 + ((lq ^ ((rb >> 1) & 3)) << 3)];
        }
#pragma unroll
        for (int i = 0; i < 4; i++)
#pragma unroll
            for (int j = 0; j < 4; j++)
                acc[i][j] = __builtin_amdgcn_mfma_f32_16x16x32_bf16(af[i], bfr[j], acc[i][j], 0, 0, 0);
        if (more) writeA(smem + (cur ^ 1) * 8192);
        __syncthreads();
    }

    // prefetch W2 frags for k0=0
    uint4 wb[2][4];
#pragma unroll
    for (int t4 = 0; t4 < 4; t4++)
        wb[0][t4] = *(const uint4*)&W2b[(long)(wn + t4 * 16 + lr) * CCH + lq * 8];

    // ---- epilogue A: h = relu(acc + b1) -> Ht (swizzled) ----
    {
        float bv[4];
#pragma unroll
        for (int j = 0; j < 4; j++) bv[j] = b1[wn + j * 16 + lr];
#pragma unroll
        for (int i = 0; i < 4; i++)
#pragma unroll
            for (int r = 0; r < 4; r++) {
                int row = wm + i * 16 + lq * 4 + r;
                int rx  = (row & 7) << 3;
#pragma unroll
                for (int j = 0; j < 4; j++)
                    Ht[row * 128 + ((wn + j * 16 + lr) ^ rx)] = f2bf(fmaxf(acc[i][j][r] + bv[j], 0.f));
            }
    }
    __syncthreads();

    // ---- phase B: acc2 = h @ W2^T (K=128), barrier-free ----
    f32x4 acc2[4][4] = {};
#pragma unroll
    for (int kk = 0; kk < 4; kk++) {
        const int k0 = kk * 32;
        if (kk < 3) {
#pragma unroll
            for (int t4 = 0; t4 < 4; t4++)
                wb[(kk + 1) & 1][t4] =
                    *(const uint4*)&W2b[(long)(wn + t4 * 16 + lr) * CCH + k0 + 32 + lq * 8];
        }
        bf16x8 af[4];
#pragma unroll
        for (int t4 = 0; t4 < 4; t4++) {
            int ra = wm + t4 * 16 + lr;
            af[t4] = *(bf16x8*)&Ht[ra * 128 + ((k0 + lq * 8) ^ ((ra & 7) << 3))];
        }
#pragma unroll
        for (int i = 0; i < 4; i++)
#pragma unroll
            for (int j = 0; j < 4; j++)
                acc2[i][j] = __builtin_amdgcn_mfma_f32_16x16x32_bf16(af[i], *(bf16x8*)&wb[kk & 1][j],
                                                                     acc2[i][j], 0, 0, 0);
    }
    __syncthreads();

    // ---- epilogue B: z -> Ht (swizzled) -> coalesced store ----
#pragma unroll
    for (int i = 0; i < 4; i++)
#pragma unroll
        for (int r = 0; r < 4; r++) {
            int row = wm + i * 16 + lq * 4 + r;
            int rx  = (row & 7) << 3;
#pragma unroll
            for (int j = 0; j < 4; j++)
                Ht[row * 128 + ((wn + j * 16 + lr) ^ rx)] = f2bf(acc2[i][j][r]);
        }
    __syncthreads();
    {
        int colq = tid & 15, row0 = tid >> 4;
#pragma unroll
        for (int i = 0; i < 8; i++) {
            int row = row0 + i * 16;
            if (m0 + row < M)
                *(uint4*)&Zq[(long)(m0 + row) * CCH + colq * 8] =
                    *(uint4*)&Ht[row * 128 + ((colq * 8) ^ ((row & 7) << 3))];
        }
    }
}

// ---------------- U1: partition (XCD-contiguous chunk remap, FIRST) ∪ gemm half A ----------------
__global__ __launch_bounds__(256)
void u_part_gemm(const int* __restrict__ src, const int* __restrict__ dst,
                 const int* __restrict__ histC, const int* __restrict__ histPre,
                 const int* __restrict__ btot, int* __restrict__ gbase,
                 unsigned* __restrict__ pairs, int E, int ncp, int nchunks,
                 const float* __restrict__ X, const ushort* __restrict__ W1b,
                 const ushort* __restrict__ W2b, const float* __restrict__ b1,
                 ushort* __restrict__ Zq, int M)
{
    __shared__ unsigned smem4[8192];    // 32 KB, carved per path
    const int bid = blockIdx.x;
    if (bid < nchunks) {
        const int x = bid & 7, i = bid >> 3;
        const int q = nchunks >> 3, r = nchunks & 7;
        const int chunk = (x < r) ? x * (q + 1) + i : r * (q + 1) + (x - r) * q + i;
        partition_body(smem4, src, dst, histC, histPre, btot, gbase, pairs, E, ncp, chunk);
    } else {
        gemm_body(smem4, X, W1b, W2b, b1, Zq, M, (bid - nchunks) * 128);
    }
}

// ---------------- U2: bucket CSR (FIRST) ∪ gemm half B ----------------
__global__ __launch_bounds__(256)
void u_csr_gemm(const unsigned* __restrict__ pairs, const int* __restrict__ base,
                int* __restrict__ row_start, float* __restrict__ dinv,
                unsigned* __restrict__ csr, int N, int E, int nbuck, int ngA,
                const float* __restrict__ X, const ushort* __restrict__ W1b,
                const ushort* __restrict__ W2b, const float* __restrict__ b1,
                ushort* __restrict__ Zq, int M)
{
    __shared__ unsigned smem4[8192];
    const int bid = blockIdx.x;
    if (bid < nbuck)
        csr_body(smem4, pairs, base, row_start, dinv, csr, N, E, bid, nbuck - 1);
    else
        gemm_body(smem4, X, W1b, W2b, b1, Zq, M, (ngA + bid - nbuck) * 128);
}

// ---------------- K6: gather — masked 8-deep batches + NEXT-BATCH INDEX PREFETCH ----------------
// [R10: masked-8 removed the serial tail, 80->72us. Remaining chain per batch was
//  csr-load -> z-load -> FMA (2 serial latencies). Prefetch batch k+1's csr indices while
//  batch k's z loads are in flight -> 1 latency per batch. +16 VGPR (~48 < 64 cliff, m69).]
__global__ __launch_bounds__(256)
void gather_nodes(const unsigned* __restrict__ zq, const unsigned* __restrict__ csr,
                  const int* __restrict__ row_start, const float* __restrict__ dinv,
                  const float* __restrict__ b2, float* __restrict__ out, int N)
{
    const int node = blockIdx.x * 4 + (threadIdx.x >> 6);
    const int lane = threadIdx.x & 63;
    if (node >= N) return;

    const float di = dinv[node];
    float2 zs = bf2f2(zq[(long)node * 64 + lane]);
    float acc0 = di * zs.x, acc1 = di * zs.y;      // self-loop: dinv[d]*z[d]

    const int rs = row_start[node];
    const int re = row_start[node + 1];

    unsigned sI[8];
#pragma unroll
    for (int q = 0; q < 8; q++) {
        int idx = min(rs + q, re - 1);
        sI[q] = csr[idx < 0 ? 0 : idx];            // prime batch (deg-0 safe)
    }
    for (int j = rs; j < re; j += 8) {
        unsigned zv[8];
        float dv[8];
#pragma unroll
        for (int q = 0; q < 8; q++) zv[q] = zq[(long)sI[q] * 64 + lane];   // issue z loads
#pragma unroll
        for (int q = 0; q < 8; q++) dv[q] = (j + q < re) ? dinv[sI[q]] : 0.f;
        unsigned sN[8];                                                     // prefetch next idx
#pragma unroll
        for (int q = 0; q < 8; q++) sN[q] = csr[min(j + 8 + q, re - 1)];
#pragma unroll
        for (int q = 0; q < 8; q++) { float2 f = bf2f2(zv[q]); acc0 += dv[q] * f.x; acc1 += dv[q] * f.y; }
#pragma unroll
        for (int q = 0; q < 8; q++) sI[q] = sN[q];
    }

    float2 o;
    o.x = b2[lane * 2 + 0] + di * acc0;
    o.y = b2[lane * 2 + 1] + di * acc1;
    *(float2*)&out[(long)node * CCH + lane * 2] = o;
}

extern "C" void kernel_launch(void* const* d_in, const int* in_sizes, int n_in,
                              void* d_out, int out_size, void* d_ws, size_t ws_size,
                              hipStream_t stream)
{
    const float* x  = (const float*)d_in[0];
    const int*   ei = (const int*)d_in[1];
    const float* W1 = (const float*)d_in[2];
    const float* b1 = (const float*)d_in[3];
    const float* W2 = (const float*)d_in[4];
    const float* b2 = (const float*)d_in[5];
    float* out = (float*)d_out;

    const int N = in_sizes[0] / F_IN;
    const int E = in_sizes[1] / 2;
    const int* src = ei;
    const int* dst = ei + E;

    const int nchunks = (E + CHUNK - 1) / CHUNK;        // 391
    const int ncp     = (nchunks + 63) & ~63;           // 448
    const int nbuck   = (N + BNODES - 1) / BNODES;      // 782
    const int ngrid   = (N + 127) / 128;                // 782
    const int ngA     = (ngrid + 1) / 2;                // 391 (gemm half A)
    const int ngB     = ngrid - ngA;                    // 391 (gemm half B)
    const int ncvt    = (CCH * F_IN + CCH * CCH + 255) / 256;

    char* ws = (char*)d_ws;
    ushort* zq    = (ushort*)ws;   ws += (size_t)N * CCH * 2;
    ushort* w1b   = (ushort*)ws;   ws += (size_t)CCH * F_IN * 2;
    ushort* w2b   = (ushort*)ws;   ws += (size_t)CCH * CCH * 2;
    unsigned* prs = (unsigned*)ws; ws += (size_t)E * 4;
    unsigned* csr = (unsigned*)ws; ws += (size_t)E * 4;
    int* rstart   = (int*)ws;      ws += ((size_t)N + 1) * 4;
    float* dinv   = (float*)ws;    ws += (size_t)N * 4;
    int* histC    = (int*)ws;      ws += (size_t)nchunks * NBUCK * 4;
    int* histT    = (int*)ws;      ws += (size_t)NBUCK * ncp * 4;
    int* btot     = (int*)ws;      ws += NBUCK * 4;
    int* gbase    = (int*)ws;      ws += (NBUCK + 1) * 4;

    // K1: histogram (tiled histT) + weight cvt
    hist_cvt<<<nchunks + ncvt, 256, 0, stream>>>(dst, histC, histT, E, nchunks, ncp, W1, W2, w1b, w2b);
    // K2: bucket prefix IN PLACE in tiled histT
    scan_buckets<<<NBUCK / 16, 1024, 0, stream>>>(histT, btot, nchunks, ncp);
    // U1: partition (XCD-remapped, first) ∪ gemm-half-A
    u_part_gemm<<<nchunks + ngA, 256, 0, stream>>>(src, dst, histC, histT, btot, gbase, prs,
                                                   E, ncp, nchunks, x, w1b, w2b, b1, zq, N);
    // U2: bucket-CSR (first) ∪ gemm-half-B
    u_csr_gemm<<<nbuck + ngB, 256, 0, stream>>>(prs, gbase, rstart, dinv, csr, N, E,
                                                nbuck, ngA, x, w1b, w2b, b1, zq, N);
    // K6: aggregate (applies dinv[src] * dinv[dst])
    gather_nodes<<<(N + 3) / 4, 256, 0, stream>>>((const unsigned*)zq, csr, rstart, dinv, b2, out, N);
}